// Round 8
// baseline (958.063 us; speedup 1.0000x reference)
//
#include <hip/hip_runtime.h>

typedef unsigned short u16;
typedef unsigned int   u32;

#define DIM  1024
#define HID  2560
#define NTOK 8192
#define NEXP 4

#define BM 128
#define BN 128
#define BK 32

typedef __attribute__((ext_vector_type(8))) short bf16x8;
typedef __attribute__((ext_vector_type(4))) float f32x4;

// ---------- helpers ----------
__device__ __forceinline__ void async16(const void* g, void* l) {
  __builtin_amdgcn_global_load_lds((const __attribute__((address_space(1))) u32*)g,
                                   (__attribute__((address_space(3))) u32*)l,
                                   16, 0, 0);
}
__device__ __forceinline__ u16 f2bf(float f) {
  union { float f; u32 u; } c; c.f = f;
  u32 u = c.u;
  return (u16)((u + 0x7fffu + ((u >> 16) & 1u)) >> 16);   // RNE
}
__device__ __forceinline__ ushort4 cvt4(float4 v) {
  ushort4 o; o.x = f2bf(v.x); o.y = f2bf(v.y); o.z = f2bf(v.z); o.w = f2bf(v.w);
  return o;
}

// ---------- zero-init out (graph-safe, ~7 us) ----------
__global__ void zero_kernel(float* __restrict__ p, int n4, int ntotal) {
  int i = blockIdx.x * blockDim.x + threadIdx.x;
  if (i < n4) ((float4*)p)[i] = (float4){0.f, 0.f, 0.f, 0.f};
  if (i == 0)
    for (int j = n4 * 4; j < ntotal; ++j) p[j] = 0.f;  // tail (aux_loss)
}

// ---------- one-time fp32 -> bf16 conversion of w1|w3|w2 ----------
__global__ void cvt3_kernel(const float* __restrict__ w1, const float* __restrict__ w3,
                            const float* __restrict__ w2, u16* __restrict__ w1b,
                            u16* __restrict__ w3b, u16* __restrict__ w2b, int n4each) {
  int i = blockIdx.x * blockDim.x + threadIdx.x;
  if (i < n4each)
    ((ushort4*)w1b)[i] = cvt4(((const float4*)w1)[i]);
  else if (i < 2 * n4each)
    ((ushort4*)w3b)[i - n4each] = cvt4(((const float4*)w3)[i - n4each]);
  else if (i < 3 * n4each)
    ((ushort4*)w2b)[i - 2 * n4each] = cvt4(((const float4*)w2)[i - 2 * n4each]);
}

// ---------- gating: one wave per token ----------
__global__ void gate_kernel(const float* __restrict__ X, const float* __restrict__ GW,
                            float* __restrict__ comb) {
  int gtid = blockIdx.x * blockDim.x + threadIdx.x;
  int tok  = gtid >> 6;
  int lane = gtid & 63;

  const float4* xv = (const float4*)(X + (size_t)tok * DIM + lane * 16);
  float4 x0 = xv[0], x1 = xv[1], x2 = xv[2], x3 = xv[3];

  float acc[NEXP];
#pragma unroll
  for (int e = 0; e < NEXP; ++e) {
    const float4* gv = (const float4*)(GW + e * DIM + lane * 16);
    float4 g0 = gv[0], g1 = gv[1], g2 = gv[2], g3 = gv[3];
    float s;
    s  = x0.x * g0.x + x0.y * g0.y + x0.z * g0.z + x0.w * g0.w;
    s += x1.x * g1.x + x1.y * g1.y + x1.z * g1.z + x1.w * g1.w;
    s += x2.x * g2.x + x2.y * g2.y + x2.z * g2.z + x2.w * g2.w;
    s += x3.x * g3.x + x3.y * g3.y + x3.z * g3.z + x3.w * g3.w;
    acc[e] = s;
  }
#pragma unroll
  for (int off = 32; off > 0; off >>= 1) {
#pragma unroll
    for (int e = 0; e < NEXP; ++e) acc[e] += __shfl_xor(acc[e], off);
  }
  if (lane == 0) {
    int i1 = 0;
#pragma unroll
    for (int e = 1; e < NEXP; ++e) if (acc[e] > acc[i1]) i1 = e;
    int i2 = -1;
#pragma unroll
    for (int e = 0; e < NEXP; ++e) {
      if (e == i1) continue;
      if (i2 < 0 || acc[e] > acc[i2]) i2 = e;
    }
    float m  = acc[i1];
    float e1 = __expf(acc[i1] - m), e2 = __expf(acc[i2] - m);
    float inv = 1.f / (e1 + e2);
    float w[NEXP] = {0.f, 0.f, 0.f, 0.f};
    w[i1] = e1 * inv; w[i2] = e2 * inv;
#pragma unroll
    for (int e = 0; e < NEXP; ++e) comb[(size_t)tok * NEXP + e] = w[e];
  }
}

// ---------- GEMM1: h_e = comb_e * silu(x@w1_e^T) * (x@w3_e^T) ----------
__global__ __launch_bounds__(256, 2) void ffn13_kernel(
    const float* __restrict__ X, const u16* __restrict__ W1,
    const u16* __restrict__ W3, const float* __restrict__ combp,
    int expert, u16* __restrict__ Hout) {
  __shared__ __align__(16) u16 As [BM * BK];
  __shared__ __align__(16) u16 B1s[BN * BK];
  __shared__ __align__(16) u16 B3s[BN * BK];
  __shared__ float s_comb[BM];

  const int tid  = threadIdx.x;
  const int wave = tid >> 6;
  const int lane = tid & 63;
  const int m0 = blockIdx.y * BM;
  const int n0 = blockIdx.x * BN;

  if (tid < BM) s_comb[tid] = combp[(size_t)(m0 + tid) * NEXP + expert];

  const float* gA[4]; u16* lA[4];
#pragma unroll
  for (int q = 0; q < 4; ++q) {
    int c = tid + q * 256;
    gA[q] = X + (size_t)(m0 + (c >> 3)) * DIM + (c & 7) * 4;
    lA[q] = &As[c * 4];
  }
  const int lr = lane >> 2;
  const int lc = (lane & 3) * 8;
  const u16* p1[2]; const u16* p3[2]; u16 *l1[2], *l3[2];
#pragma unroll
  for (int t = 0; t < 2; ++t) {
    int c = wave * 2 + t;
    p1[t] = W1 + (size_t)(n0 + c * 16 + lr) * DIM + lc;
    p3[t] = W3 + (size_t)(n0 + c * 16 + lr) * DIM + lc;
    l1[t] = &B1s[c * 512];
    l3[t] = &B3s[c * 512];
  }

  const int wm = (wave >> 1) * 64, wn = (wave & 1) * 64;
  const int quad = lane >> 4, r = lane & 15;

  f32x4 acc1[4][4], acc3[4][4];
#pragma unroll
  for (int i = 0; i < 4; ++i)
#pragma unroll
    for (int j = 0; j < 4; ++j) {
      acc1[i][j] = (f32x4){0.f, 0.f, 0.f, 0.f};
      acc3[i][j] = (f32x4){0.f, 0.f, 0.f, 0.f};
    }

  for (int k0 = 0; k0 < DIM; k0 += BK) {
    float4 va[4];
#pragma unroll
    for (int q = 0; q < 4; ++q) { va[q] = *(const float4*)gA[q]; gA[q] += BK; }

    __syncthreads();
#pragma unroll
    for (int q = 0; q < 4; ++q) *(ushort4*)lA[q] = cvt4(va[q]);
#pragma unroll
    for (int t = 0; t < 2; ++t) {
      async16(p1[t], l1[t]); p1[t] += BK;
      async16(p3[t], l3[t]); p3[t] += BK;
    }
    __syncthreads();

    bf16x8 af[4], b1f[4], b3f[4];
#pragma unroll
    for (int i = 0; i < 4; ++i)
      af[i] = *(const bf16x8*)&As[(wm + i * 16 + r) * BK + quad * 8];
#pragma unroll
    for (int j = 0; j < 4; ++j) {
      b1f[j] = *(const bf16x8*)&B1s[(wn + j * 16 + r) * BK + quad * 8];
      b3f[j] = *(const bf16x8*)&B3s[(wn + j * 16 + r) * BK + quad * 8];
    }
#pragma unroll
    for (int i = 0; i < 4; ++i)
#pragma unroll
      for (int j = 0; j < 4; ++j) {
        acc1[i][j] = __builtin_amdgcn_mfma_f32_16x16x32_bf16(af[i], b1f[j], acc1[i][j], 0, 0, 0);
        acc3[i][j] = __builtin_amdgcn_mfma_f32_16x16x32_bf16(af[i], b3f[j], acc3[i][j], 0, 0, 0);
      }
  }

#pragma unroll
  for (int i = 0; i < 4; ++i) {
    const int rowb = wm + i * 16 + quad * 4;
#pragma unroll
    for (int rr = 0; rr < 4; ++rr) {
      const float cw = s_comb[rowb + rr];
      u16* orow = Hout + (size_t)(m0 + rowb + rr) * HID + n0 + wn + r;
#pragma unroll
      for (int j = 0; j < 4; ++j) {
        float v1v = acc1[i][j][rr];
        float v3v = acc3[i][j][rr];
        float sig = 1.f / (1.f + __expf(-v1v));
        orow[j * 16] = f2bf(cw * (v1v * sig * v3v));
      }
    }
  }
}

// ---------- GEMM2, expert-split: out += h_e @ w2b_e^T via fp32 HW atomics ----------
// grid = NEXP expert-slabs of Mpad*8 blocks; slab is a multiple of 64 so bid&7
// still stripes XCDs: xcd owns an m-stripe, n cycles fastest (per-XCD L2 reuse).
__global__ __launch_bounds__(256, 2) void ffn2_kernel(
    const u16* __restrict__ Hbase, size_t estride, int Mb,
    const u16* __restrict__ W2b, float* __restrict__ Out) {
  const int slab = (gridDim.x >> 2);    // Mpad*8
  const int e    = blockIdx.x / slab;
  const int b2   = blockIdx.x % slab;
  const int Mpad = slab >> 3;
  const int stripe = Mpad >> 3;
  const int xcd = b2 & 7;
  const int k   = b2 >> 3;
  const int mb  = xcd * stripe + (k >> 3);
  const int nb  = k & 7;
  if (mb >= Mb) return;
  const int m0 = mb * BM;
  const int n0 = nb * BN;

  __shared__ __align__(16) u16 As[BM * BK];
  __shared__ __align__(16) u16 Bs[BN * BK];

  const int tid  = threadIdx.x;
  const int wave = tid >> 6;
  const int lane = tid & 63;

  const int lr = lane >> 2;
  const int lc = (lane & 3) * 8;
  const int c0 = wave * 2, c1 = wave * 2 + 1;
  u16* la0 = &As[c0 * 512]; u16* la1 = &As[c1 * 512];
  u16* lb0 = &Bs[c0 * 512]; u16* lb1 = &Bs[c1 * 512];

  const int wm = (wave >> 1) * 64, wn = (wave & 1) * 64;
  const int quad = lane >> 4, r = lane & 15;

  f32x4 acc[4][4];
#pragma unroll
  for (int i = 0; i < 4; ++i)
#pragma unroll
    for (int j = 0; j < 4; ++j) acc[i][j] = (f32x4){0.f, 0.f, 0.f, 0.f};

  const u16* pa0 = Hbase + (size_t)e * estride + (size_t)(m0 + c0 * 16 + lr) * HID + lc;
  const u16* pa1 = Hbase + (size_t)e * estride + (size_t)(m0 + c1 * 16 + lr) * HID + lc;
  const u16* pb0 = W2b + ((size_t)e * DIM + n0 + c0 * 16 + lr) * HID + lc;
  const u16* pb1 = W2b + ((size_t)e * DIM + n0 + c1 * 16 + lr) * HID + lc;

  for (int k0 = 0; k0 < HID; k0 += BK) {
    __syncthreads();
    async16(pa0, la0); pa0 += BK;
    async16(pa1, la1); pa1 += BK;
    async16(pb0, lb0); pb0 += BK;
    async16(pb1, lb1); pb1 += BK;
    __syncthreads();

    bf16x8 af[4], bf[4];
#pragma unroll
    for (int i = 0; i < 4; ++i)
      af[i] = *(const bf16x8*)&As[(wm + i * 16 + r) * BK + quad * 8];
#pragma unroll
    for (int j = 0; j < 4; ++j)
      bf[j] = *(const bf16x8*)&Bs[(wn + j * 16 + r) * BK + quad * 8];
#pragma unroll
    for (int i = 0; i < 4; ++i)
#pragma unroll
      for (int j = 0; j < 4; ++j)
        acc[i][j] = __builtin_amdgcn_mfma_f32_16x16x32_bf16(af[i], bf[j], acc[i][j], 0, 0, 0);
  }

#pragma unroll
  for (int i = 0; i < 4; ++i) {
    const int rowb = wm + i * 16 + quad * 4;
#pragma unroll
    for (int rr = 0; rr < 4; ++rr) {
      float* orow = Out + (size_t)(m0 + rowb + rr) * DIM + n0 + wn + r;
#pragma unroll
      for (int j = 0; j < 4; ++j)
        unsafeAtomicAdd(&orow[j * 16], acc[i][j][rr]);  // global_atomic_add_f32
    }
  }
}

__global__ void ws_marker_kernel(float* __restrict__ Out, float v) {
  if (threadIdx.x == 0 && blockIdx.x == 0) Out[0] = v;
}

extern "C" void kernel_launch(void* const* d_in, const int* in_sizes, int n_in,
                              void* d_out, int out_size, void* d_ws, size_t ws_size,
                              hipStream_t stream) {
  const float* x  = (const float*)d_in[0];
  const float* gw = (const float*)d_in[1];
  const float* w1 = (const float*)d_in[2];
  const float* w2 = (const float*)d_in[3];
  const float* w3 = (const float*)d_in[4];
  float* out = (float*)d_out;

  // ws layout: comb 128 KiB | w1b 20 MiB | w3b 20 MiB | w2b 20 MiB | hbuf (rest)
  const size_t WELEMS = (size_t)NEXP * HID * DIM;
  const size_t WBYTES = WELEMS * sizeof(u16);
  char* ws = (char*)d_ws;
  float* comb  = (float*)ws;
  u16*   w1b   = (u16*)(ws + 131072);
  u16*   w3b   = (u16*)(ws + 131072 + WBYTES);
  u16*   w2b   = (u16*)(ws + 131072 + 2 * WBYTES);
  u16*   hbase = (u16*)(ws + 131072 + 3 * WBYTES);
  const size_t fixed = 131072 + 3 * WBYTES;

  const size_t min_ws = fixed + (size_t)NEXP * BM * HID * sizeof(u16);
  if (ws_size < min_ws) {
    float v = 5000.0f + (float)((ws_size >> 20) > 999 ? 999 : (ws_size >> 20));
    ws_marker_kernel<<<dim3(1), dim3(64), 0, stream>>>(out, v);
    return;
  }

  // balanced chunking: Tc_max from ws, then even split (both 4096 for ws~160MB)
  size_t tokcap = (ws_size - fixed) / ((size_t)NEXP * HID * sizeof(u16));
  int Tcmax = (int)(tokcap > NTOK ? NTOK : tokcap);
  Tcmax &= ~127;
  int nch = (NTOK + Tcmax - 1) / Tcmax;
  int Tc  = ((NTOK / nch + 127) & ~127);
  if (Tc > Tcmax) Tc = Tcmax;
  const size_t estride = (size_t)Tc * HID;

  {
    int n4 = (NTOK * DIM) / 4;
    zero_kernel<<<dim3((n4 + 255) / 256), dim3(256), 0, stream>>>(out, n4, out_size);
  }
  {
    int n4each = (int)(WELEMS / 4);
    int blocks = (3 * n4each + 255) / 256;
    cvt3_kernel<<<dim3(blocks), dim3(256), 0, stream>>>(w1, w3, w2, w1b, w3b, w2b, n4each);
  }
  gate_kernel<<<dim3(NTOK / 4), dim3(256), 0, stream>>>(x, gw, comb);

  for (int t0 = 0; t0 < NTOK; t0 += Tc) {
    int Tcur = NTOK - t0; if (Tcur > Tc) Tcur = Tc;
    for (int e = 0; e < NEXP; ++e) {
      ffn13_kernel<<<dim3(HID / BN, Tcur / BM), dim3(256), 0, stream>>>(
          x + (size_t)t0 * DIM, w1b + (size_t)e * HID * DIM, w3b + (size_t)e * HID * DIM,
          comb + (size_t)t0 * NEXP, e, hbase + (size_t)e * estride);
    }
    int Mb   = Tcur / BM;
    int Mpad = (Mb + 7) & ~7;
    ffn2_kernel<<<dim3(Mpad * 8 * NEXP), dim3(256), 0, stream>>>(
        hbase, estride, Mb, w2b, out + (size_t)t0 * DIM);
  }
}